// Round 1
// baseline (444.667 us; speedup 1.0000x reference)
//
#include <hip/hip_runtime.h>

// Hierarchy: B0=8, B1=16, B2=16; BATCH=32768.
// out[b, (a0*16+a1)*16 + a2] =
//   cumprod(dc0[b])[a0] * cumprod_grp16(dc1[b])[a0,a1] * cumprod_grp16(dc2[b])[a0*16+a1, a2]

#define NB0 8
#define NB1 16
#define NB2 16
#define GROUPS (NB0 * NB1)      // 128 groups of 16 leaves
#define ROW_LEN (GROUPS * NB2)  // 2048

__global__ __launch_bounds__(512)
void det_prob_kernel(const float* __restrict__ dc0,
                     const float* __restrict__ dc1,
                     const float* __restrict__ dc2,
                     float* __restrict__ out)
{
    __shared__ float s_dc1[GROUPS];
    __shared__ float s_prefix[GROUPS];

    const int row = blockIdx.x;
    const int t   = threadIdx.x;

    const size_t row_off  = (size_t)row * ROW_LEN;
    const size_t row_off1 = (size_t)row * GROUPS;

    // ---- Phase 1a: stage dc1 row into LDS (coalesced) ----
    if (t < GROUPS) {
        s_dc1[t] = dc1[row_off1 + t];
    }
    __syncthreads();

    // ---- Phase 1b: threads 0..7 build prefix[] for their a0 group ----
    if (t < NB0) {
        const int a0 = t;
        // cumprod(dc0)[a0]
        float c0 = 1.0f;
        #pragma unroll
        for (int k = 0; k < NB0; ++k) {
            float v = dc0[(size_t)row * NB0 + k];
            if (k <= a0) c0 *= v;
        }
        // prefix[a0*16 + j] = c0 * cumprod(dc1 group a0)[j]
        float run = c0;
        #pragma unroll
        for (int j = 0; j < NB1; ++j) {
            run *= s_dc1[a0 * NB1 + j];
            s_prefix[a0 * NB1 + j] = run;
        }
    }
    __syncthreads();

    // ---- Phase 2: each thread handles one float4 of dc2 (coalesced) ----
    const int g = t >> 2;  // group of 16 leaves; 4 lanes per group

    const float4 x = reinterpret_cast<const float4*>(dc2 + row_off)[t];
    float y0 = x.x;
    float y1 = y0 * x.y;
    float y2 = y1 * x.z;
    float y3 = y2 * x.w;

    // quad-level exclusive prefix of the 4-element totals (all in one wave)
    const int lane  = t & 63;
    const int qbase = lane & ~3;
    const int j     = lane & 3;
    const float tot = y3;
    const float t0 = __shfl(tot, qbase + 0);
    const float t1 = __shfl(tot, qbase + 1);
    const float t2 = __shfl(tot, qbase + 2);

    float p = s_prefix[g];  // quad-broadcast, conflict-free
    if (j > 0) p *= t0;
    if (j > 1) p *= t1;
    if (j > 2) p *= t2;

    float4 o;
    o.x = y0 * p;
    o.y = y1 * p;
    o.z = y2 * p;
    o.w = y3 * p;
    reinterpret_cast<float4*>(out + row_off)[t] = o;
}

extern "C" void kernel_launch(void* const* d_in, const int* in_sizes, int n_in,
                              void* d_out, int out_size, void* d_ws, size_t ws_size,
                              hipStream_t stream) {
    const float* dc0 = (const float*)d_in[0];
    const float* dc1 = (const float*)d_in[1];
    const float* dc2 = (const float*)d_in[2];
    float* out = (float*)d_out;

    const int batch = in_sizes[0] / NB0;  // 32768
    det_prob_kernel<<<batch, 512, 0, stream>>>(dc0, dc1, dc2, out);
}

// Round 2
// 431.468 us; speedup vs baseline: 1.0306x; 1.0306x over previous
//
#include <hip/hip_runtime.h>

// Hierarchy: B0=8, B1=16, B2=16; BATCH=32768.
// out[b, (a0*16+a1)*16 + a2] =
//   cumprod(dc0[b])[a0] * cumprod_grp16(dc1[b])[a0,a1] * cumprod_grp16(dc2[b])[a0*16+a1, a2]
//
// Wave-autonomous layout: block = 512 threads = 8 waves = 1 row.
// Wave w owns a0 = w (16 sibling groups, 4 lanes per group).
// No LDS, no __syncthreads — dc2 load issued first to hide prefix math.

#define NB0 8
#define NB1 16
#define NB2 16
#define GROUPS (NB0 * NB1)      // 128 groups of 16 leaves
#define ROW_LEN (GROUPS * NB2)  // 2048

__global__ __launch_bounds__(512)
void det_prob_kernel(const float* __restrict__ dc0,
                     const float* __restrict__ dc1,
                     const float* __restrict__ dc2,
                     float* __restrict__ out)
{
    const int row = blockIdx.x;
    const int t   = threadIdx.x;

    const size_t row_off = (size_t)row * ROW_LEN;

    // ---- Issue the big load FIRST: one float4 of dc2 per thread (coalesced) ----
    const float4 x = reinterpret_cast<const float4*>(dc2 + row_off)[t];

    const int wave = t >> 6;   // == a0 for this wave
    const int lane = t & 63;
    const int j    = lane & 3; // position of this quad-lane within its group-of-16

    // ---- c0 = cumprod(dc0[row])[a0]; dc0 addr is block-uniform -> scalar loads ----
    float c0 = 1.0f;
    #pragma unroll
    for (int k = 0; k < NB0; ++k) {
        float v = dc0[(size_t)row * NB0 + k];
        if (k <= wave) c0 *= v;
    }

    // ---- dc1 value for this lane's group (4-way broadcast within wave) ----
    // group-local index within the wave's a0 slab = lane >> 2  (a1)
    float d1 = dc1[(size_t)row * GROUPS + (size_t)wave * NB1 + (lane >> 2)];

    // Inclusive scan of d1 across the 16 groups via lane-scan with quad-sized
    // steps (all 4 lanes of a quad hold the same value, so offsets 4/8/16/32
    // give exactly the per-group Hillis-Steele scan).
    float scan = d1;
    #pragma unroll
    for (int off = 4; off <= 32; off <<= 1) {
        float u = __shfl_up(scan, off, 64);
        if (lane >= off) scan *= u;
    }
    const float prefix = c0 * scan;  // c0 * cumprod(dc1 group)[a1], inclusive

    // ---- local cumprod of the 4 dc2 elements ----
    float y0 = x.x;
    float y1 = y0 * x.y;
    float y2 = y1 * x.z;
    float y3 = y2 * x.w;

    // quad-level exclusive prefix of the per-lane totals
    const int qbase = lane & ~3;
    const float t0 = __shfl(y3, qbase + 0, 64);
    const float t1 = __shfl(y3, qbase + 1, 64);
    const float t2 = __shfl(y3, qbase + 2, 64);

    float p = prefix;
    if (j > 0) p *= t0;
    if (j > 1) p *= t1;
    if (j > 2) p *= t2;

    float4 o;
    o.x = y0 * p;
    o.y = y1 * p;
    o.z = y2 * p;
    o.w = y3 * p;
    reinterpret_cast<float4*>(out + row_off)[t] = o;
}

extern "C" void kernel_launch(void* const* d_in, const int* in_sizes, int n_in,
                              void* d_out, int out_size, void* d_ws, size_t ws_size,
                              hipStream_t stream) {
    const float* dc0 = (const float*)d_in[0];
    const float* dc1 = (const float*)d_in[1];
    const float* dc2 = (const float*)d_in[2];
    float* out = (float*)d_out;

    const int batch = in_sizes[0] / NB0;  // 32768
    det_prob_kernel<<<batch, 512, 0, stream>>>(dc0, dc1, dc2, out);
}